// Round 2
// baseline (175.722 us; speedup 1.0000x reference)
//
#include <hip/hip_runtime.h>

// Problem constants (from reference): x shape (8,32,256,256), K=3, stride 1, no pad.
#define B_   8
#define C_   32
#define H_   256
#define W_   256
#define BC_  (B_ * C_)
#define HO_  (H_ - 2)          // 254
#define WO_  (W_ - 2)          // 254
#define NIN_  (BC_ * H_ * W_)  // 16,777,216
#define NOUT_ (BC_ * HO_ * WO_) // 16,516,096
#define NBINS 256

// Module-owned global histogram — NOT in d_ws (d_ws proved unsafe: writing it
// corrupted the harness's pristine-input copy; first call passed, all
// post-restore calls failed with absmax 255). Re-zeroed every call.
__device__ int g_hist[NBINS];

__global__ void zero_hist_kernel() {
    g_hist[threadIdx.x] = 0;
}

// Grid-stride float4 histogram; 4 per-wave LDS sub-histograms to cut LDS-atomic contention.
__global__ __launch_bounds__(256) void hist_kernel(const float* __restrict__ x) {
    __shared__ int sh[4 * NBINS];
    const int t = threadIdx.x;
    for (int i = t; i < 4 * NBINS; i += 256) sh[i] = 0;
    __syncthreads();

    const int wave = t >> 6;
    int* myh = &sh[wave * NBINS];
    const float4* x4 = (const float4*)x;
    const int n4 = NIN_ / 4;
    for (int idx = blockIdx.x * 256 + t; idx < n4; idx += gridDim.x * 256) {
        float4 v = x4[idx];
        atomicAdd(&myh[(int)v.x], 1);
        atomicAdd(&myh[(int)v.y], 1);
        atomicAdd(&myh[(int)v.z], 1);
        atomicAdd(&myh[(int)v.w], 1);
    }
    __syncthreads();

    for (int b = t; b < NBINS; b += 256) {
        int s = sh[b] + sh[NBINS + b] + sh[2 * NBINS + b] + sh[3 * NBINS + b];
        if (s) atomicAdd(&g_hist[b], s);
    }
}

// One thread per output pixel. Histogram lives in LDS (1 KB). Strict '<' keeps the
// FIRST minimum in row-major (di,dj) order — matches jnp.argmin tie-break.
__global__ __launch_bounds__(256) void pool_kernel(const float* __restrict__ x,
                                                   float* __restrict__ out) {
    __shared__ int sh[NBINS];
    const int t = threadIdx.x;
    if (t < NBINS) sh[t] = g_hist[t];
    __syncthreads();

    // NOUT_ = 64516 blocks * 256 threads exactly (254*254 = 64516).
    const long long o = (long long)blockIdx.x * 256 + t;
    const int j  = (int)(o % WO_);
    const long long r = o / WO_;
    const int i  = (int)(r % HO_);
    const int bc = (int)(r / HO_);

    const float* base = x + ((long long)bc * H_ + i) * W_ + j;

    float bestv = 0.0f;
    int bestc = 0x7fffffff;
#pragma unroll
    for (int di = 0; di < 3; ++di) {
#pragma unroll
        for (int dj = 0; dj < 3; ++dj) {
            float v = base[di * W_ + dj];
            int c = sh[(int)v];
            if (c < bestc) { bestc = c; bestv = v; }
        }
    }
    out[o] = bestv;
}

extern "C" void kernel_launch(void* const* d_in, const int* in_sizes, int n_in,
                              void* d_out, int out_size, void* d_ws, size_t ws_size,
                              hipStream_t stream) {
    const float* x = (const float*)d_in[0];
    float* out = (float*)d_out;
    (void)d_ws; (void)ws_size;

    zero_hist_kernel<<<1, NBINS, 0, stream>>>();
    hist_kernel<<<1024, 256, 0, stream>>>(x);
    pool_kernel<<<NOUT_ / 256, 256, 0, stream>>>(x, out);
}

// Round 3
// 153.441 us; speedup vs baseline: 1.1452x; 1.1452x over previous
//
#include <hip/hip_runtime.h>

// x shape (8,32,256,256) float32 holding exact integers 0..255; K=3, stride 1, no pad.
#define B_   8
#define C_   32
#define H_   256
#define W_   256
#define BC_  (B_ * C_)
#define HO_  (H_ - 2)           // 254
#define WO_  (W_ - 2)           // 254
#define NIN_  (BC_ * H_ * W_)   // 16,777,216
#define NBINS 256
#define HCOLS 16                // sub-histogram columns (bank-aliasing <=4-way)

// Module-owned global histogram (d_ws proved unsafe in R1). 8-aligned for packed
// 64-bit atomics in the reduction. Re-zeroed every call.
__device__ __align__(8) int g_hist[NBINS];

__global__ void zero_hist_kernel() { g_hist[threadIdx.x] = 0; }

// Column sub-histograms: sh[bin*HCOLS + (t & 15)]. Lane's bank = (16*(bin&1) + col)
// -> at most 4-way aliasing per wave instruction instead of random 64->32-bank pileups.
__global__ __launch_bounds__(256) void hist_kernel(const float* __restrict__ x) {
    __shared__ int sh[NBINS * HCOLS];   // 16 KB
    const int t = threadIdx.x;
    for (int i = t; i < NBINS * HCOLS; i += 256) sh[i] = 0;
    __syncthreads();

    const int col = t & (HCOLS - 1);
    const float4* x4 = (const float4*)x;
    const int n4 = NIN_ / 4;
    const int stride = gridDim.x * 256;
    for (int idx = blockIdx.x * 256 + t; idx < n4; idx += 2 * stride) {
        float4 v0 = x4[idx];
        const int idx2 = idx + stride;
        if (idx2 < n4) {
            float4 v1 = x4[idx2];   // second load issued before any atomics (MLP)
            atomicAdd(&sh[((int)v0.x) * HCOLS + col], 1);
            atomicAdd(&sh[((int)v0.y) * HCOLS + col], 1);
            atomicAdd(&sh[((int)v0.z) * HCOLS + col], 1);
            atomicAdd(&sh[((int)v0.w) * HCOLS + col], 1);
            atomicAdd(&sh[((int)v1.x) * HCOLS + col], 1);
            atomicAdd(&sh[((int)v1.y) * HCOLS + col], 1);
            atomicAdd(&sh[((int)v1.z) * HCOLS + col], 1);
            atomicAdd(&sh[((int)v1.w) * HCOLS + col], 1);
        } else {
            atomicAdd(&sh[((int)v0.x) * HCOLS + col], 1);
            atomicAdd(&sh[((int)v0.y) * HCOLS + col], 1);
            atomicAdd(&sh[((int)v0.z) * HCOLS + col], 1);
            atomicAdd(&sh[((int)v0.w) * HCOLS + col], 1);
        }
    }
    __syncthreads();

    // Rotated-index column reduction (conflict-light), pair-packed 64-bit global atomic.
    if (t < 128) {
        const int b0 = 2 * t, b1 = 2 * t + 1;
        int s0 = 0, s1 = 0;
#pragma unroll
        for (int c = 0; c < HCOLS; ++c) {
            const int cc = (c + t) & (HCOLS - 1);
            s0 += sh[b0 * HCOLS + cc];
            s1 += sh[b1 * HCOLS + cc];
        }
        unsigned long long packed =
            (unsigned long long)(unsigned int)s0 | ((unsigned long long)(unsigned int)s1 << 32);
        atomicAdd((unsigned long long*)&g_hist[b0], packed);
    }
}

// Block = one (bc, 16-output-row strip). Load 18x256 input tile once, ONE histogram
// lookup per input element, store fused key = (count<<8)|value in LDS. Compute reads
// keys stride-1 (2-way bank alias = free) with 3-register row rotation: 3 new LDS
// reads per output. Argmin on (key & ~255) strict '<' == exact positional first-min.
__global__ __launch_bounds__(256) void pool_kernel(const float* __restrict__ x,
                                                   float* __restrict__ out) {
    __shared__ int hist_s[NBINS];
    __shared__ int tile[18 * W_];   // 18 KB
    const int t = threadIdx.x;
    hist_s[t] = g_hist[t];
    __syncthreads();

    const int bc = blockIdx.x >> 4;
    const int s  = blockIdx.x & 15;
    const int r0 = s * 16;
    const int rows_out = (r0 + 16 <= HO_) ? 16 : (HO_ - r0);  // 16, last strip 14
    const int rows_in  = rows_out + 2;                        // 18 / 16 (fits H_)

    const float4* xin = (const float4*)(x + ((long long)bc * H_ + r0) * W_);
    const int nf4 = rows_in * (W_ / 4);
    for (int idx = t; idx < nf4; idx += 256) {
        float4 v = xin[idx];
        const int vx = (int)v.x, vy = (int)v.y, vz = (int)v.z, vw = (int)v.w;
        int4 k;
        k.x = (hist_s[vx] << 8) | vx;
        k.y = (hist_s[vy] << 8) | vy;
        k.z = (hist_s[vz] << 8) | vz;
        k.w = (hist_s[vw] << 8) | vw;
        ((int4*)tile)[idx] = k;
    }
    __syncthreads();

    if (t >= WO_) return;   // no further barriers below

    int a0 = tile[t],        a1 = tile[t + 1],        a2 = tile[t + 2];
    int b0 = tile[W_ + t],   b1 = tile[W_ + t + 1],   b2 = tile[W_ + t + 2];
    float* orow = out + ((long long)bc * HO_ + r0) * WO_ + t;
    for (int r = 0; r < rows_out; ++r) {
        const int base = (r + 2) * W_ + t;
        const int c0 = tile[base], c1 = tile[base + 1], c2 = tile[base + 2];
        int best = a0, bm = a0 & ~255;
#define CAND(kk) { const int m = (kk) & ~255; if (m < bm) { bm = m; best = (kk); } }
        CAND(a1) CAND(a2) CAND(b0) CAND(b1) CAND(b2) CAND(c0) CAND(c1) CAND(c2)
#undef CAND
        orow[(long long)r * WO_] = (float)(best & 255);
        a0 = b0; a1 = b1; a2 = b2;
        b0 = c0; b1 = c1; b2 = c2;
    }
}

extern "C" void kernel_launch(void* const* d_in, const int* in_sizes, int n_in,
                              void* d_out, int out_size, void* d_ws, size_t ws_size,
                              hipStream_t stream) {
    const float* x = (const float*)d_in[0];
    float* out = (float*)d_out;
    (void)d_ws; (void)ws_size;

    zero_hist_kernel<<<1, NBINS, 0, stream>>>();
    hist_kernel<<<1024, 256, 0, stream>>>(x);
    pool_kernel<<<BC_ * 16, 256, 0, stream>>>(x, out);
}